// Round 12
// baseline (159.095 us; speedup 1.0000x reference)
//
#include <hip/hip_runtime.h>
#include <hip/hip_bf16.h>
#include <math.h>

#define B 32
#define KLEN 2000
#define KDIM 512
#define QDIM 512
#define ADIM 512
#define VDIM 512
#define CONV_CH 10
#define CONV_K 201
#define NROWS (B*KLEN)

#define NKS  33                  // 528 / 16 (512 key + 10 conv + 1 bias + 5 pad)
#define KTILES 63                // ceil(2000/32) key-row tiles per batch
#define ZERO16 {0,0,0,0,0,0,0,0,0,0,0,0,0,0,0,0}

// prep-kernel grid split
#define NP_PACK 53               // ceil(33792/640)
#define NP_QPRJ 26               // ceil(16384/640)
#define NP_ZERO 26               // ceil(16384/640) zero cv
#define NP_CONV 256              // 32 b x 8 chunks of 256 k

#define CH_LEN 63                // cvpart: 32 chunks x 63 >= 2000

typedef __attribute__((ext_vector_type(8)))  short bf16x8;
typedef __attribute__((ext_vector_type(16))) float f32x16;
typedef __attribute__((ext_vector_type(4)))  float f32x4;

__device__ __forceinline__ ushort f32_to_bf16(float f) {
    union { float f; unsigned int u; } v; v.f = f;
    unsigned int x = v.u;
    unsigned int r = (x + 0x7FFFu + ((x >> 16) & 1u)) >> 16;
    return (ushort)r;
}

__device__ __forceinline__ unsigned int pk_bf16(float lo, float hi) {
    // v_cvt_pk_bf16_f32 (RNE) via HIP intrinsic; identical rounding to f32_to_bf16
    union { __hip_bfloat162 h2; unsigned int u; } c;
    float2 t; t.x = lo; t.y = hi;
    c.h2 = __float22bfloat162_rn(t);
    return c.u;
}

__device__ __forceinline__ float fast_tanh(float x) {
    // tanh(x) = 1 - 2/(e^(2x)+1); stable at both extremes
    return 1.0f - 2.0f / (__expf(2.0f * x) + 1.0f);
}

#define MFMA32(a, bfr, c) __builtin_amdgcn_mfma_f32_32x32x16_bf16(a, bfr, c, 0, 0, 0)

// ---- K0: fused prep: pack W_ext | qproj | zero cv | conv ----------------
__global__ __launch_bounds__(640, 2)
void k_prep(const float* __restrict__ Wk, const float* __restrict__ Wconv,
            const float* __restrict__ bk, ushort* __restrict__ wp,
            const float* __restrict__ query, const float* __restrict__ Wq,
            float* __restrict__ qproj,
            const float* __restrict__ aw_prev, const float* __restrict__ conv_w,
            float* __restrict__ cf, float* __restrict__ cv) {
    __shared__ float w_s[CONV_CH * 204];     // taps zero-padded to 204
    __shared__ float aw_s[464];              // k0-100 .. k0+363
    const int bid = blockIdx.x, tid = threadIdx.x;

    if (bid < NP_PACK) {
        // pack W_ext = [Wk | Wconv | bk | 0pad] -> wp
        // layout: [nt(16)][ks(33)][lane(64)][8 bf16]; lane = h*32+r;
        // holds W_ext[a = nt*32 + r][k = ks*16 + h*8 + jj]
        int t = bid * 640 + tid;
        if (t < 16 * NKS * 64) {
            int lane = t & 63;
            int idx = t >> 6;
            int ks = idx % NKS, nt = idx / NKS;
            int h = lane >> 5, r = lane & 31;
            int a = nt * 32 + r;
            int j0 = ks * 16 + h * 8;
            union { uint4 v; ushort u[8]; } pk;
            #pragma unroll
            for (int jj = 0; jj < 8; jj++) {
                int j = j0 + jj;
                float val;
                if (j < 512)       val = Wk[a * KDIM + j];
                else if (j < 522)  val = Wconv[a * CONV_CH + (j - 512)];
                else if (j == 522) val = bk[a];
                else               val = 0.f;
                pk.u[jj] = f32_to_bf16(val);
            }
            *(uint4*)(wp + (size_t)t * 8) = pk.v;
        }
    } else if (bid < NP_PACK + NP_QPRJ) {
        int t = (bid - NP_PACK) * 640 + tid;
        if (t < B * ADIM) {
            int b = t >> 9, a = t & 511;
            const f32x4* q = (const f32x4*)(query + b * QDIM);
            const f32x4* w = (const f32x4*)(Wq + a * QDIM);
            float acc = 0.f;
            #pragma unroll 4
            for (int i = 0; i < 128; i++) {
                f32x4 qv = q[i], wv = w[i];
                acc += qv[0]*wv[0] + qv[1]*wv[1] + qv[2]*wv[2] + qv[3]*wv[3];
            }
            qproj[t] = acc;
        }
    } else if (bid < NP_PACK + NP_QPRJ + NP_ZERO) {
        int t = (bid - NP_PACK - NP_QPRJ) * 640 + tid;
        if (t < B * VDIM) cv[t] = 0.f;
    } else {
        // conv: register-sliding-window cross-correlation
        int cb = bid - NP_PACK - NP_QPRJ - NP_ZERO;
        int b = cb >> 3, chunk = cb & 7;
        int k0 = chunk * 256;
        for (int i = tid; i < CONV_CH * 204; i += 640) {
            int c = i / 204, t = i % 204;
            w_s[i] = (t < CONV_K) ? conv_w[c * CONV_K + t] : 0.f;
        }
        for (int i = tid; i < 464; i += 640) {
            int src = k0 - 100 + i;
            aw_s[i] = (src >= 0 && src < KLEN) ? aw_prev[b * KLEN + src] : 0.f;
        }
        __syncthreads();

        const int c = tid >> 6;                    // wave = channel
        const int k_local = (tid & 63) * 4;
        const float* wc = w_s + c * 204;
        float a0 = 0.f, a1 = 0.f, a2 = 0.f, a3 = 0.f;
        f32x4 r0 = *(const f32x4*)(aw_s + k_local);
        #pragma unroll 3
        for (int q = 0; q < 51; q++) {
            f32x4 r1 = *(const f32x4*)(aw_s + k_local + 4 * q + 4);
            float w0 = wc[4*q], w1 = wc[4*q+1], w2 = wc[4*q+2], w3 = wc[4*q+3];
            a0 += w0*r0[0]; a1 += w0*r0[1]; a2 += w0*r0[2]; a3 += w0*r0[3];
            a0 += w1*r0[1]; a1 += w1*r0[2]; a2 += w1*r0[3]; a3 += w1*r1[0];
            a0 += w2*r0[2]; a1 += w2*r0[3]; a2 += w2*r1[0]; a3 += w2*r1[1];
            a0 += w3*r0[3]; a1 += w3*r1[0]; a2 += w3*r1[1]; a3 += w3*r1[2];
            r0 = r1;
        }
        int k = k0 + k_local;
        float* dst = cf + ((size_t)b * CONV_CH + c) * KLEN + k;
        if (k + 3 < KLEN) {
            f32x4 o; o[0] = a0; o[1] = a1; o[2] = a2; o[3] = a3;
            *(f32x4*)dst = o;
        } else {
            if (k     < KLEN) dst[0] = a0;
            if (k + 1 < KLEN) dst[1] = a1;
            if (k + 2 < KLEN) dst[2] = a2;
            if (k + 3 < KLEN) dst[3] = a3;
        }
    }
}

// ---- K3: fused kproj-ext GEMM + additive score (swapped operands) -------
// Block: 32 key rows x 512 a-cols; 8 waves of 64 cols x 32 rows (acc = 32 regs).
// D[row=a][col=keyrow]: lane owns one keyrow -> per-lane serial tanh-dot.
__global__ __launch_bounds__(512, 4)
void k_main(const float* __restrict__ key, const ushort* __restrict__ wp,
            const float* __restrict__ qproj, const float* __restrict__ cf,
            const float* __restrict__ vvec, const int* __restrict__ mask,
            float* __restrict__ e_out) {
    __shared__ char Alds[32768];                   // 32 key rows x 512 bf16, swizzled
    __shared__ float partsum[8][32];               // [wave][keyrow] partial e
    const int tid = threadIdx.x;
    const int wc = tid >> 6, lane = tid & 63;      // wc = a-colgroup 0..7 (64 cols)
    const int r = lane & 31, h = lane >> 5;
    const int b = blockIdx.x / KTILES;             // batch
    const int kbase = (blockIdx.x % KTILES) * 32;  // first key pos of block

    // ---- stage 32 key rows (f32 -> bf16 via cvt_pk) into swizzled LDS ---
    #pragma unroll
    for (int i = 0; i < 4; i++) {
        int ch = tid + i * 512;                    // 2048 chunks of 16B
        int arow = ch >> 6, cx = ch & 63;
        int kpos = kbase + arow; if (kpos >= KLEN) kpos = KLEN - 1;  // clamp tail
        const float* kp = key + ((size_t)b * KLEN + kpos) * KDIM + cx * 8;
        f32x4 f0 = __builtin_nontemporal_load((const f32x4*)kp);
        f32x4 f1 = __builtin_nontemporal_load((const f32x4*)(kp + 4));
        uint4 pk;
        pk.x = pk_bf16(f0[0], f0[1]);
        pk.y = pk_bf16(f0[2], f0[3]);
        pk.z = pk_bf16(f1[0], f1[1]);
        pk.w = pk_bf16(f1[2], f1[3]);
        int off = (arow << 10) + (cx << 4);
        off ^= (arow & 31) << 4;
        *(uint4*)(Alds + off) = pk;
    }
    __syncthreads();

    // ---- main loop: W (A-op) from L2, key (B-op) from LDS ---------------
    const ushort* bpW0 = wp + ((size_t)(wc * 2 + 0) * NKS * 64 + lane) * 8;
    const ushort* bpW1 = wp + ((size_t)(wc * 2 + 1) * NKS * 64 + lane) * 8;
    const int koff = r * 1024 + h * 16;
    const int swz = r << 4;

    f32x16 c0 = ZERO16, c1 = ZERO16;

    #pragma unroll 4
    for (int ks = 0; ks < 32; ks++) {
        bf16x8 kf = *(const bf16x8*)(Alds + ((koff + ks * 32) ^ swz));
        bf16x8 w0 = *(const bf16x8*)(bpW0 + ks * 512);
        bf16x8 w1 = *(const bf16x8*)(bpW1 + ks * 512);
        c0 = MFMA32(w0, kf, c0);
        c1 = MFMA32(w1, kf, c1);
    }
    {   // ks = 32: conv features + bias-one column (B-op built in registers)
        int kc = kbase + r; if (kc >= KLEN) kc = KLEN - 1;
        const float* cfb = cf + ((size_t)b * CONV_CH) * KLEN + kc;
        union { bf16x8 v8; unsigned int u[4]; ushort us[8]; } pk;
        if (h == 0) {
            pk.u[0] = pk_bf16(cfb[0],              cfb[(size_t)1 * KLEN]);
            pk.u[1] = pk_bf16(cfb[(size_t)2*KLEN], cfb[(size_t)3 * KLEN]);
            pk.u[2] = pk_bf16(cfb[(size_t)4*KLEN], cfb[(size_t)5 * KLEN]);
            pk.u[3] = pk_bf16(cfb[(size_t)6*KLEN], cfb[(size_t)7 * KLEN]);
        } else {
            pk.u[0] = pk_bf16(cfb[(size_t)8*KLEN], cfb[(size_t)9 * KLEN]);
            pk.us[2] = 0x3F80;  // 1.0f bf16 (bias column)
            pk.us[3] = 0;
            pk.u[2] = 0; pk.u[3] = 0;
        }
        bf16x8 w0 = *(const bf16x8*)(bpW0 + 32 * 512);
        bf16x8 w1 = *(const bf16x8*)(bpW1 + 32 * 512);
        c0 = MFMA32(w0, pk.v8, c0);
        c1 = MFMA32(w1, pk.v8, c1);
    }

    // ---- epilogue: + qproj, tanh, * v — per-lane serial -----------------
    // acc reg i -> a = wc*64 + t*32 + (i&3) + 8*(i>>2) + 4*h
    const float* qb = qproj + b * ADIM + wc * 64;
    const float* vb = vvec + wc * 64;
    float pg = 0.f;
    #pragma unroll
    for (int t = 0; t < 2; t++) {
        const f32x16 ac = t ? c1 : c0;
        #pragma unroll
        for (int q = 0; q < 4; q++) {
            f32x4 qv = *(const f32x4*)(qb + t * 32 + 8 * q + 4 * h);
            f32x4 vv = *(const f32x4*)(vb + t * 32 + 8 * q + 4 * h);
            #pragma unroll
            for (int j = 0; j < 4; j++)
                pg += fast_tanh(ac[4 * q + j] + qv[j]) * vv[j];
        }
    }
    pg += __shfl_xor(pg, 32);      // merge h-halves (cover all 64 a of the group)
    if (h == 0) partsum[wc][r] = pg;
    __syncthreads();

    // ---- combine 8 col-groups, mask, write e ----------------------------
    if (tid < 32) {
        float s = 0.f;
        #pragma unroll
        for (int w = 0; w < 8; w++) s += partsum[w][tid];
        int kpos = kbase + tid;
        if (kpos < KLEN) {
            int idx = b * KLEN + kpos;
            e_out[idx] = mask[idx] ? s : -3.4028235e38f;
        }
    }
}

// ---- K4: per-batch softmax stats {m, 1/s} -------------------------------
__global__ void k_stats(const float* __restrict__ e, float* __restrict__ stats) {
    int b = blockIdx.x;
    const float* er = e + b * KLEN;
    __shared__ float redm[4], reds[4];
    int tid = threadIdx.x, lane = tid & 63, wv = tid >> 6;
    float m = -3.4028235e38f;
    for (int k = tid; k < KLEN; k += 256) m = fmaxf(m, er[k]);
    for (int o = 32; o; o >>= 1) m = fmaxf(m, __shfl_xor(m, o));
    if (lane == 0) redm[wv] = m;
    __syncthreads();
    m = fmaxf(fmaxf(redm[0], redm[1]), fmaxf(redm[2], redm[3]));
    float s = 0.f;
    for (int k = tid; k < KLEN; k += 256) s += __expf(er[k] - m);
    for (int o = 32; o; o >>= 1) s += __shfl_xor(s, o);
    if (lane == 0) reds[wv] = s;
    __syncthreads();
    if (tid == 0) {
        s = reds[0] + reds[1] + reds[2] + reds[3];
        stats[b * 2] = m;
        stats[b * 2 + 1] = 1.0f / s;
    }
}

// ---- K5: cv partial with inline softmax apply + aw write + atomic cv ----
__global__ __launch_bounds__(512, 4)
void k_cvpart(const float* __restrict__ e, const float* __restrict__ stats,
              const float* __restrict__ value, float* __restrict__ aw,
              float* __restrict__ cv) {
    int b = blockIdx.x >> 5, chunk = blockIdx.x & 31;   // 32 chunks of 63 k
    int k0 = chunk * CH_LEN;
    int len = KLEN - k0; if (len > CH_LEN) len = CH_LEN;
    __shared__ float sa[CH_LEN + 1];
    __shared__ f32x4 red[3][128];
    int tid = threadIdx.x;
    if (tid < len) {
        float m = stats[b * 2], inv = stats[b * 2 + 1];
        float p = __expf(e[b * KLEN + k0 + tid] - m) * inv;
        sa[tid] = p;
        aw[b * KLEN + k0 + tid] = p;
    }
    __syncthreads();
    const int kh = tid >> 7;            // 0..3
    const int colt = tid & 127;
    const float* vp = value + ((size_t)b * KLEN + k0) * VDIM + colt * 4;
    f32x4 acc = {0.f, 0.f, 0.f, 0.f};
    for (int k = kh; k < len; k += 4) {
        f32x4 vv = *(const f32x4*)(vp + (size_t)k * VDIM);
        acc += vv * sa[k];
    }
    if (kh) red[kh - 1][colt] = acc;
    __syncthreads();
    if (kh == 0) {
        acc += red[0][colt] + red[1][colt] + red[2][colt];
        float* dst = cv + b * VDIM + colt * 4;
        atomicAdd(dst + 0, acc[0]);
        atomicAdd(dst + 1, acc[1]);
        atomicAdd(dst + 2, acc[2]);
        atomicAdd(dst + 3, acc[3]);
    }
}

extern "C" void kernel_launch(void* const* d_in, const int* in_sizes, int n_in,
                              void* d_out, int out_size, void* d_ws, size_t ws_size,
                              hipStream_t stream) {
    const float* key     = (const float*)d_in[0];
    const float* value   = (const float*)d_in[1];
    const float* query   = (const float*)d_in[2];
    const float* aw_prev = (const float*)d_in[3];
    const int*   mask    = (const int*)d_in[4];
    const float* Wk      = (const float*)d_in[5];
    const float* bk      = (const float*)d_in[6];
    const float* Wq      = (const float*)d_in[7];
    const float* conv_w  = (const float*)d_in[8];
    const float* Wconv   = (const float*)d_in[9];
    const float* vvec    = (const float*)d_in[10];

    char* ws = (char*)d_ws;
    ushort* wp   = (ushort*)(ws + 0);          // 16*33*64*8*2 = 540672
    float* qproj = (float*)(ws + 540672);      // 32*512*4     = 65536
    float* cf    = (float*)(ws + 606208);      // 32*10*2000*4 = 2560000
    float* e     = (float*)(ws + 3166208);     // 32*2000*4    = 256000
    float* stats = (float*)(ws + 3422208);     // 32*2*4       = 256

    float* cv = (float*)d_out;                 // [32][512]
    float* aw = (float*)d_out + B * VDIM;      // [32][2000]

    k_prep  <<<NP_PACK + NP_QPRJ + NP_ZERO + NP_CONV, 640, 0, stream>>>(
                Wk, Wconv, bk, wp, query, Wq, qproj, aw_prev, conv_w, cf, cv);
    k_main  <<<B * KTILES, 512, 0, stream>>>(key, wp, qproj, cf, vvec, mask, e);
    k_stats <<<B,    256, 0, stream>>>(e, stats);
    k_cvpart<<<B*32, 512, 0, stream>>>(e, stats, value, aw, cv);
}

// Round 13
// 140.088 us; speedup vs baseline: 1.1357x; 1.1357x over previous
//
#include <hip/hip_runtime.h>
#include <hip/hip_bf16.h>
#include <math.h>

#define B 32
#define KLEN 2000
#define KDIM 512
#define QDIM 512
#define ADIM 512
#define VDIM 512
#define CONV_CH 10
#define CONV_K 201
#define NROWS (B*KLEN)

#define NKS  33                  // 528 / 16 (512 key + 10 conv + 1 bias + 5 pad)
#define ZERO16 {0,0,0,0,0,0,0,0,0,0,0,0,0,0,0,0}

// prep-kernel grid split
#define NP_PACK 53               // ceil(33792/640)
#define NP_QPRJ 26               // ceil(16384/640)
#define NP_ZERO 26               // ceil(16384/640) zero cv
#define NP_CONV 256              // 32 b x 8 chunks of 256 k

#define CH_LEN 63                // cv: 32 chunks x 63 >= 2000

typedef __attribute__((ext_vector_type(8)))  short bf16x8;
typedef __attribute__((ext_vector_type(16))) float f32x16;
typedef __attribute__((ext_vector_type(4)))  float f32x4;

__device__ __forceinline__ ushort f32_to_bf16(float f) {
    union { float f; unsigned int u; } v; v.f = f;
    unsigned int x = v.u;
    unsigned int r = (x + 0x7FFFu + ((x >> 16) & 1u)) >> 16;
    return (ushort)r;
}

__device__ __forceinline__ unsigned int pk_bf16(float lo, float hi) {
    // v_cvt_pk_bf16_f32 (RNE) — identical rounding to f32_to_bf16
    union { __hip_bfloat162 h2; unsigned int u; } c;
    float2 t; t.x = lo; t.y = hi;
    c.h2 = __float22bfloat162_rn(t);
    return c.u;
}

__device__ __forceinline__ float fast_tanh(float x) {
    // tanh(x) = 1 - 2/(e^(2x)+1); stable at both extremes
    return 1.0f - 2.0f / (__expf(2.0f * x) + 1.0f);
}

#define MFMA32(a, bfr, c) __builtin_amdgcn_mfma_f32_32x32x16_bf16(a, bfr, c, 0, 0, 0)

// ---- K0: fused prep: pack W_ext | qproj | zero cv | conv ----------------
__global__ __launch_bounds__(640, 2)
void k_prep(const float* __restrict__ Wk, const float* __restrict__ Wconv,
            const float* __restrict__ bk, ushort* __restrict__ wp,
            const float* __restrict__ query, const float* __restrict__ Wq,
            float* __restrict__ qproj,
            const float* __restrict__ aw_prev, const float* __restrict__ conv_w,
            float* __restrict__ cf, float* __restrict__ cv) {
    __shared__ float w_s[CONV_CH * 204];     // taps zero-padded to 204
    __shared__ float aw_s[464];              // k0-100 .. k0+363
    const int bid = blockIdx.x, tid = threadIdx.x;

    if (bid < NP_PACK) {
        // pack W_ext = [Wk | Wconv | bk | 0pad] -> wp
        // layout: [nt(16)][ks(33)][lane(64)][8 bf16]; lane = h*32+r;
        // holds W_ext[a = nt*32 + r][k = ks*16 + h*8 + jj]
        int t = bid * 640 + tid;
        if (t < 16 * NKS * 64) {
            int lane = t & 63;
            int idx = t >> 6;
            int ks = idx % NKS, nt = idx / NKS;
            int h = lane >> 5, r = lane & 31;
            int a = nt * 32 + r;
            int j0 = ks * 16 + h * 8;
            union { uint4 v; ushort u[8]; } pk;
            #pragma unroll
            for (int jj = 0; jj < 8; jj++) {
                int j = j0 + jj;
                float val;
                if (j < 512)       val = Wk[a * KDIM + j];
                else if (j < 522)  val = Wconv[a * CONV_CH + (j - 512)];
                else if (j == 522) val = bk[a];
                else               val = 0.f;
                pk.u[jj] = f32_to_bf16(val);
            }
            *(uint4*)(wp + (size_t)t * 8) = pk.v;
        }
    } else if (bid < NP_PACK + NP_QPRJ) {
        int t = (bid - NP_PACK) * 640 + tid;
        if (t < B * ADIM) {
            int b = t >> 9, a = t & 511;
            const f32x4* q = (const f32x4*)(query + b * QDIM);
            const f32x4* w = (const f32x4*)(Wq + a * QDIM);
            float acc = 0.f;
            #pragma unroll 4
            for (int i = 0; i < 128; i++) {
                f32x4 qv = q[i], wv = w[i];
                acc += qv[0]*wv[0] + qv[1]*wv[1] + qv[2]*wv[2] + qv[3]*wv[3];
            }
            qproj[t] = acc;
        }
    } else if (bid < NP_PACK + NP_QPRJ + NP_ZERO) {
        int t = (bid - NP_PACK - NP_QPRJ) * 640 + tid;
        if (t < B * VDIM) cv[t] = 0.f;
    } else {
        // conv: register-sliding-window cross-correlation
        int cb = bid - NP_PACK - NP_QPRJ - NP_ZERO;
        int b = cb >> 3, chunk = cb & 7;
        int k0 = chunk * 256;
        for (int i = tid; i < CONV_CH * 204; i += 640) {
            int c = i / 204, t = i % 204;
            w_s[i] = (t < CONV_K) ? conv_w[c * CONV_K + t] : 0.f;
        }
        for (int i = tid; i < 464; i += 640) {
            int src = k0 - 100 + i;
            aw_s[i] = (src >= 0 && src < KLEN) ? aw_prev[b * KLEN + src] : 0.f;
        }
        __syncthreads();

        const int c = tid >> 6;                    // wave = channel
        const int k_local = (tid & 63) * 4;
        const float* wc = w_s + c * 204;
        float a0 = 0.f, a1 = 0.f, a2 = 0.f, a3 = 0.f;
        f32x4 r0 = *(const f32x4*)(aw_s + k_local);
        #pragma unroll 3
        for (int q = 0; q < 51; q++) {
            f32x4 r1 = *(const f32x4*)(aw_s + k_local + 4 * q + 4);
            float w0 = wc[4*q], w1 = wc[4*q+1], w2 = wc[4*q+2], w3 = wc[4*q+3];
            a0 += w0*r0[0]; a1 += w0*r0[1]; a2 += w0*r0[2]; a3 += w0*r0[3];
            a0 += w1*r0[1]; a1 += w1*r0[2]; a2 += w1*r0[3]; a3 += w1*r1[0];
            a0 += w2*r0[2]; a1 += w2*r0[3]; a2 += w2*r1[0]; a3 += w2*r1[1];
            a0 += w3*r0[3]; a1 += w3*r1[0]; a2 += w3*r1[1]; a3 += w3*r1[2];
            r0 = r1;
        }
        int k = k0 + k_local;
        float* dst = cf + ((size_t)b * CONV_CH + c) * KLEN + k;
        if (k + 3 < KLEN) {
            f32x4 o; o[0] = a0; o[1] = a1; o[2] = a2; o[3] = a3;
            *(f32x4*)dst = o;
        } else {
            if (k     < KLEN) dst[0] = a0;
            if (k + 1 < KLEN) dst[1] = a1;
            if (k + 2 < KLEN) dst[2] = a2;
            if (k + 3 < KLEN) dst[3] = a3;
        }
    }
}

// ---- K1: fused kproj-ext GEMM + additive score (swapped operands) -------
// R8 structure (best measured): 64 keyrows x 512 cols, 8 waves x (64c x 64r),
// key in 64KB swizzled LDS, W from L2, acc = 4 x f32x16.
__global__ __launch_bounds__(512, 4)
void k_main(const float* __restrict__ key, const ushort* __restrict__ wp,
            const float* __restrict__ qproj, const float* __restrict__ cf,
            const float* __restrict__ vvec, const int* __restrict__ mask,
            float* __restrict__ e_out) {
    __shared__ char Alds[65536];                   // 64 key rows x 512 bf16, swizzled
    __shared__ float partsum[8][2][32];            // [wave][g][r] partial e
    const int tid = threadIdx.x;
    const int wc = tid >> 6, lane = tid & 63;      // wc = a-colgroup 0..7
    const int r = lane & 31, h = lane >> 5;
    const int b = blockIdx.x >> 5;                 // batch
    const int kbase = (blockIdx.x & 31) * 64;      // first key pos of block

    // ---- stage key rows (f32 -> bf16 via cvt_pk) into swizzled LDS ------
    #pragma unroll
    for (int i = 0; i < 8; i++) {
        int ch = tid + i * 512;
        int arow = ch >> 6, cx = ch & 63;
        int kpos = kbase + arow; if (kpos >= KLEN) kpos = KLEN - 1;  // clamp tail
        const float* kp = key + ((size_t)b * KLEN + kpos) * KDIM + cx * 8;
        f32x4 f0 = __builtin_nontemporal_load((const f32x4*)kp);
        f32x4 f1 = __builtin_nontemporal_load((const f32x4*)(kp + 4));
        uint4 pk;
        pk.x = pk_bf16(f0[0], f0[1]);
        pk.y = pk_bf16(f0[2], f0[3]);
        pk.z = pk_bf16(f1[0], f1[1]);
        pk.w = pk_bf16(f1[2], f1[3]);
        int off = (arow << 10) + (cx << 4);
        off ^= (arow & 31) << 4;
        *(uint4*)(Alds + off) = pk;
    }
    __syncthreads();

    // ---- main loop: W (A-op) from L2, key (B-op) from LDS ---------------
    const ushort* bpW0 = wp + ((size_t)(wc * 2 + 0) * NKS * 64 + lane) * 8;
    const ushort* bpW1 = wp + ((size_t)(wc * 2 + 1) * NKS * 64 + lane) * 8;
    const int base_g0 = r * 1024 + h * 16;
    const int base_g1 = base_g0 + 32768;
    const int swz = r << 4;

    f32x16 c00 = ZERO16, c01 = ZERO16;             // c[t][g]
    f32x16 c10 = ZERO16, c11 = ZERO16;

    #pragma unroll 4
    for (int ks = 0; ks < 32; ks++) {
        bf16x8 k0 = *(const bf16x8*)(Alds + ((base_g0 + ks * 32) ^ swz));
        bf16x8 k1 = *(const bf16x8*)(Alds + ((base_g1 + ks * 32) ^ swz));
        bf16x8 w0 = *(const bf16x8*)(bpW0 + ks * 512);
        bf16x8 w1 = *(const bf16x8*)(bpW1 + ks * 512);
        c00 = MFMA32(w0, k0, c00); c01 = MFMA32(w0, k1, c01);
        c10 = MFMA32(w1, k0, c10); c11 = MFMA32(w1, k1, c11);
    }
    {   // ks = 32: conv features + bias-one columns (B-op built in registers)
        auto build_ext = [&](int kpos) -> bf16x8 {
            int kc = kpos < KLEN ? kpos : KLEN - 1;
            const float* cfb = cf + ((size_t)b * CONV_CH) * KLEN + kc;
            union { bf16x8 v8; unsigned int u[4]; ushort us[8]; } pk;
            if (h == 0) {
                pk.u[0] = pk_bf16(cfb[0],              cfb[(size_t)1 * KLEN]);
                pk.u[1] = pk_bf16(cfb[(size_t)2*KLEN], cfb[(size_t)3 * KLEN]);
                pk.u[2] = pk_bf16(cfb[(size_t)4*KLEN], cfb[(size_t)5 * KLEN]);
                pk.u[3] = pk_bf16(cfb[(size_t)6*KLEN], cfb[(size_t)7 * KLEN]);
            } else {
                pk.u[0] = pk_bf16(cfb[(size_t)8*KLEN], cfb[(size_t)9 * KLEN]);
                pk.us[2] = 0x3F80;  // 1.0f bf16 (bias column)
                pk.us[3] = 0;
                pk.u[2] = 0; pk.u[3] = 0;
            }
            return pk.v8;
        };
        bf16x8 x0 = build_ext(kbase + r);
        bf16x8 x1 = build_ext(kbase + 32 + r);
        bf16x8 w0 = *(const bf16x8*)(bpW0 + 32 * 512);
        bf16x8 w1 = *(const bf16x8*)(bpW1 + 32 * 512);
        c00 = MFMA32(w0, x0, c00); c01 = MFMA32(w0, x1, c01);
        c10 = MFMA32(w1, x0, c10); c11 = MFMA32(w1, x1, c11);
    }

    // ---- epilogue: + qproj, tanh, * v — all per-lane --------------------
    const float* qb = qproj + b * ADIM + wc * 64;
    const float* vb = vvec + wc * 64;
    float pg0 = 0.f, pg1 = 0.f;
    #pragma unroll
    for (int t = 0; t < 2; t++) {
        const f32x16 a0 = t ? c10 : c00;
        const f32x16 a1 = t ? c11 : c01;
        #pragma unroll
        for (int q = 0; q < 4; q++) {
            f32x4 qv = *(const f32x4*)(qb + t * 32 + 8 * q + 4 * h);
            f32x4 vv = *(const f32x4*)(vb + t * 32 + 8 * q + 4 * h);
            #pragma unroll
            for (int j = 0; j < 4; j++) {
                int i = 4 * q + j;
                pg0 += fast_tanh(a0[i] + qv[j]) * vv[j];
                pg1 += fast_tanh(a1[i] + qv[j]) * vv[j];
            }
        }
    }
    pg0 += __shfl_xor(pg0, 32);
    pg1 += __shfl_xor(pg1, 32);
    if (h == 0) { partsum[wc][0][r] = pg0; partsum[wc][1][r] = pg1; }
    __syncthreads();

    if (tid < 64) {
        int g = tid >> 5, rr = tid & 31;
        float s = 0.f;
        #pragma unroll
        for (int w = 0; w < 8; w++) s += partsum[w][g][rr];
        int kpos = kbase + g * 32 + rr;
        if (kpos < KLEN) {
            int idx = b * KLEN + kpos;
            e_out[idx] = mask[idx] ? s : -3.4028235e38f;
        }
    }
}

// ---- K2: fused stats + softmax apply + aw write + cv atomic accumulate --
// Each block recomputes its batch's {m, 1/s} from e (L2-hot, ~4 loads/thread)
// then processes its 63-k chunk: p -> aw, p.value -> atomicAdd cv.
__global__ __launch_bounds__(512, 4)
void k_cv(const float* __restrict__ e, const float* __restrict__ value,
          float* __restrict__ aw, float* __restrict__ cv) {
    int b = blockIdx.x >> 5, chunk = blockIdx.x & 31;   // 32 chunks of 63 k
    const float* er = e + b * KLEN;
    __shared__ float redv[8];
    __shared__ float sa[CH_LEN + 1];
    __shared__ f32x4 red[3][128];
    int tid = threadIdx.x, lane = tid & 63, wv = tid >> 6;

    // ---- per-batch max ---------------------------------------------------
    float m = -3.4028235e38f;
    for (int k = tid; k < KLEN; k += 512) m = fmaxf(m, er[k]);
    for (int o = 32; o; o >>= 1) m = fmaxf(m, __shfl_xor(m, o));
    if (lane == 0) redv[wv] = m;
    __syncthreads();
    m = fmaxf(fmaxf(fmaxf(redv[0], redv[1]), fmaxf(redv[2], redv[3])),
              fmaxf(fmaxf(redv[4], redv[5]), fmaxf(redv[6], redv[7])));
    __syncthreads();
    // ---- per-batch sum ---------------------------------------------------
    float s = 0.f;
    for (int k = tid; k < KLEN; k += 512) s += __expf(er[k] - m);
    for (int o = 32; o; o >>= 1) s += __shfl_xor(s, o);
    if (lane == 0) redv[wv] = s;
    __syncthreads();
    s = redv[0] + redv[1] + redv[2] + redv[3] + redv[4] + redv[5] + redv[6] + redv[7];
    const float inv = 1.0f / s;

    // ---- chunk: softmax apply + aw write --------------------------------
    int k0 = chunk * CH_LEN;
    int len = KLEN - k0; if (len > CH_LEN) len = CH_LEN;
    if (tid < len) {
        float p = __expf(er[k0 + tid] - m) * inv;
        sa[tid] = p;
        aw[b * KLEN + k0 + tid] = p;
    }
    __syncthreads();

    // ---- value dot (4-way k split) + atomic cv --------------------------
    const int kh = tid >> 7;            // 0..3
    const int colt = tid & 127;
    const float* vp = value + ((size_t)b * KLEN + k0) * VDIM + colt * 4;
    f32x4 acc = {0.f, 0.f, 0.f, 0.f};
    for (int k = kh; k < len; k += 4) {
        f32x4 vv = *(const f32x4*)(vp + (size_t)k * VDIM);
        acc += vv * sa[k];
    }
    if (kh) red[kh - 1][colt] = acc;
    __syncthreads();
    if (kh == 0) {
        acc += red[0][colt] + red[1][colt] + red[2][colt];
        float* dst = cv + b * VDIM + colt * 4;
        atomicAdd(dst + 0, acc[0]);
        atomicAdd(dst + 1, acc[1]);
        atomicAdd(dst + 2, acc[2]);
        atomicAdd(dst + 3, acc[3]);
    }
}

extern "C" void kernel_launch(void* const* d_in, const int* in_sizes, int n_in,
                              void* d_out, int out_size, void* d_ws, size_t ws_size,
                              hipStream_t stream) {
    const float* key     = (const float*)d_in[0];
    const float* value   = (const float*)d_in[1];
    const float* query   = (const float*)d_in[2];
    const float* aw_prev = (const float*)d_in[3];
    const int*   mask    = (const int*)d_in[4];
    const float* Wk      = (const float*)d_in[5];
    const float* bk      = (const float*)d_in[6];
    const float* Wq      = (const float*)d_in[7];
    const float* conv_w  = (const float*)d_in[8];
    const float* Wconv   = (const float*)d_in[9];
    const float* vvec    = (const float*)d_in[10];

    char* ws = (char*)d_ws;
    ushort* wp   = (ushort*)(ws + 0);          // 16*33*64*8*2 = 540672
    float* qproj = (float*)(ws + 540672);      // 32*512*4     = 65536
    float* cf    = (float*)(ws + 606208);      // 32*10*2000*4 = 2560000
    float* e     = (float*)(ws + 3166208);     // 32*2000*4    = 256000

    float* cv = (float*)d_out;                 // [32][512]
    float* aw = (float*)d_out + B * VDIM;      // [32][2000]

    k_prep<<<NP_PACK + NP_QPRJ + NP_ZERO + NP_CONV, 640, 0, stream>>>(
              Wk, Wconv, bk, wp, query, Wq, qproj, aw_prev, conv_w, cf, cv);
    k_main<<<1024, 512, 0, stream>>>(key, wp, qproj, cf, vvec, mask, e);
    k_cv  <<<B*32, 512, 0, stream>>>(e, value, aw, cv);
}